// Round 10
// baseline (4464.319 us; speedup 1.0000x reference)
//
#include <hip/hip_runtime.h>

// Weighted furthest point sampling + gathers for KeypointDetector.
// B=16, N=16384, C=128, S=1024, SEM=20.
//
// FPS: 64 one-wave blocks per batch (1024 blocks). No barriers, no LDS in
// the step loop. In-wave DPP-butterfly max reduce; cross-block exchange via
// step-tagged per-block slots in global (L2-resident), 2-deep buffered.
//
// Output layout (float*, concatenated in reference return order):
//   [0, 49152)                  sampled_xyz      [B,S,3]
//   [49152, 49152+2097152)      sample_seg_feat  [B,C,S]
//   [2146304, 2162688)          sample_seg_label [B,S] (stored as float)

#define FPS_B   16
#define FPS_N   16384
#define FPS_C   128
#define FPS_S   1024
#define FPS_SEM 20
#define FPS_Q   64    // one-wave blocks per batch
#define FPS_LP  4     // points per lane = N / (Q*64)

typedef unsigned long long ull;

// 64-bit max with a DPP-permuted partner: o = v[perm(lane)], keep max.
template <int CTRL>
__device__ __forceinline__ ull dpp_max64(ull v) {
  unsigned lo = (unsigned)v, hi = (unsigned)(v >> 32);
  unsigned plo = __builtin_amdgcn_update_dpp(lo, lo, CTRL, 0xF, 0xF, true);
  unsigned phi = __builtin_amdgcn_update_dpp(hi, hi, CTRL, 0xF, 0xF, true);
  ull o = ((ull)phi << 32) | plo;
  return o > v ? o : v;
}

// Full-wave max: 4 DPP levels (xor1, xor2, xor7, xor15 — valid butterfly:
// each level merges disjoint halves of a growing group) + shfl for 16/32.
__device__ __forceinline__ ull wave_max64(ull v) {
  v = dpp_max64<0xB1>(v);    // quad_perm [1,0,3,2]  == xor 1
  v = dpp_max64<0x4E>(v);    // quad_perm [2,3,0,1]  == xor 2
  v = dpp_max64<0x141>(v);   // row_half_mirror      == xor 7 (merges 4s -> 8)
  v = dpp_max64<0x140>(v);   // row_mirror           == xor 15 (merges 8s -> 16)
  ull o = __shfl_xor(v, 16, 64); v = (o > v) ? o : v;
  o = __shfl_xor(v, 32, 64);     v = (o > v) ? o : v;
  return v;
}

// ---- prep: per-batch label histogram + zero the exchange slots ------------
__global__ __launch_bounds__(1024) void wfps_prep(
    const int* __restrict__ label,   // [B,N]
    int*       __restrict__ counts,  // [B,32]
    ull*       __restrict__ slots)   // [B][Q][2]
{
  const int b = blockIdx.x;
  const int t = threadIdx.x;
  __shared__ int c[FPS_SEM];
  if (t < FPS_SEM) c[t] = 0;
  __syncthreads();
  const int* lab = label + b * FPS_N;
#pragma unroll
  for (int k = 0; k < 16; ++k) atomicAdd(&c[lab[t + k * 1024]], 1);
  __syncthreads();
  if (t < FPS_SEM) counts[b * 32 + t] = c[t];
  if (t < FPS_Q * 2) slots[b * (FPS_Q * 2) + t] = 0ull;
}

// ---- FPS: 1024 one-wave blocks ---------------------------------------------
__global__ __launch_bounds__(64) void wfps_fps(
    const float* __restrict__ xyz,     // [B,N,3]
    const int*   __restrict__ label,   // [B,N]
    const int*   __restrict__ counts,  // [B,32]
    int*         __restrict__ idx_out, // [B,S]
    ull*         __restrict__ slots)   // [B][Q][2], pre-zeroed
{
  // blockIdx mapping: all 64 blocks of a batch share one XCD under the
  // %8 round-robin heuristic (correctness does not depend on it).
  const int i = blockIdx.x;
  const int b = (i & 7) + (((i >> 3) & 1) << 3);  // batch
  const int q = i >> 4;                            // my chunk (0..63)
  const int lane = threadIdx.x;

  // ---- my 4 points: n = q*256 + k*64 + lane (k ascending == n ascending) ---
  const float* xb = xyz + b * FPS_N * 3;
  const int* lab = label + b * FPS_N;
  const int* cb = counts + b * 32;
  float px[FPS_LP], py[FPS_LP], pz[FPS_LP], w[FPS_LP], mind[FPS_LP];
#pragma unroll
  for (int k = 0; k < FPS_LP; ++k) {
    int n = (q << 8) + (k << 6) + lane;
    px[k] = xb[n * 3 + 0];
    py[k] = xb[n * 3 + 1];
    pz[k] = xb[n * 3 + 2];
    w[k] = (float)cb[lab[n]];
    mind[k] = 1e10f;
    asm("" : "+v"(px[k]), "+v"(py[k]), "+v"(pz[k]), "+v"(w[k]));
  }

  if (q == 0 && lane == 0) idx_out[(b << 10)] = 0;
  float lx = xb[0], ly = xb[1], lz = xb[2];

  ull* sb = slots + b * (FPS_Q * 2);   // this batch's slots [q][2]

  for (int s = 1; s < FPS_S; ++s) {
    // local best over my 4 points (strict '>' keeps smallest k == smallest n)
    float bs = -1.0f;
    int bk = 0;
#pragma unroll
    for (int k = 0; k < FPS_LP; ++k) {
      // exact IEEE ops via _rn intrinsics: un-fusable, numpy summation order
      float dx = __fsub_rn(px[k], lx);
      float dy = __fsub_rn(py[k], ly);
      float dz = __fsub_rn(pz[k], lz);
      float d  = __fadd_rn(__fadd_rn(__fmul_rn(dx, dx), __fmul_rn(dy, dy)),
                           __fmul_rn(dz, dz));
      float m = fminf(mind[k], d);
      mind[k] = m;
      float sc = __fmul_rn(m, w[k]);
      bool g = sc > bs;
      bs = g ? sc : bs;
      bk = g ? k : bk;
    }
    // pack: hi32 = score bits (>=0, bit order == value order);
    // lo32 = (step_tag << 14) | (16383 - n)  -> max == smallest n on ties,
    // and the 10-bit tag makes staleness detectable (slots zeroed per call).
    unsigned n = (unsigned)((q << 8) + (bk << 6) + lane);
    ull best = ((ull)__float_as_uint(bs) << 32) |
               (ull)(((unsigned)s << 14) | (16383u - n));

    best = wave_max64(best);   // all lanes now hold the wave/block winner

    // publish my block's winner into this step's buffer (2-deep: skew <= 1)
    if (lane == 0)
      __hip_atomic_store(&sb[(q << 1) + (s & 1)], best,
                         __ATOMIC_RELAXED, __HIP_MEMORY_SCOPE_AGENT);

    // poll: lane j watches block j's slot; done when all 64 carry tag == s
    const ull* myslot = &sb[(lane << 1) + (s & 1)];
    ull v;
    do {
      v = __hip_atomic_load(myslot, __ATOMIC_RELAXED, __HIP_MEMORY_SCOPE_AGENT);
    } while (__ballot((unsigned)((v >> 14) & 0x3FF) == (unsigned)s) != ~0ull);

    ull g = wave_max64(v);     // global winner, uniform across the wave
    int cur = 16383 - (int)(g & 0x3FFF);

    if (q == 0 && lane == 0) idx_out[(b << 10) + s] = cur;

    const float* qq = xb + 3 * cur;   // uniform cached load
    lx = qq[0]; ly = qq[1]; lz = qq[2];
  }
}

// ---- single-block fallback (R7, proven) ------------------------------------
__global__ __launch_bounds__(1024)
__attribute__((amdgpu_waves_per_eu(4, 4)))
void wfps_single(
    const float* __restrict__ xyz,
    const int*   __restrict__ label,
    int*         __restrict__ idx_out)
{
  const int b = blockIdx.x;
  const int t = threadIdx.x;
  __shared__ int counts[FPS_SEM];
  __shared__ ull wmax[FPS_S];
  if (t < FPS_SEM) counts[t] = 0;
  wmax[t] = 0ull;
  __syncthreads();
  const int* lab = label + b * FPS_N;
  int mylab[16];
#pragma unroll
  for (int k = 0; k < 16; ++k) {
    mylab[k] = lab[t + k * 1024];
    atomicAdd(&counts[mylab[k]], 1);
  }
  __syncthreads();
  const float* xb = xyz + b * FPS_N * 3;
  float px[16], py[16], pz[16], w[16], mind[16];
#pragma unroll
  for (int k = 0; k < 16; ++k) {
    int n = t + k * 1024;
    px[k] = xb[n * 3 + 0];
    py[k] = xb[n * 3 + 1];
    pz[k] = xb[n * 3 + 2];
    w[k] = (float)counts[mylab[k]];
    mind[k] = 1e10f;
    asm("" : "+v"(px[k]), "+v"(py[k]), "+v"(pz[k]), "+v"(w[k]));
  }
  if (t == 0) idx_out[b * FPS_S] = 0;
  float lx = xb[0], ly = xb[1], lz = xb[2];
  for (int s = 1; s < FPS_S; ++s) {
    float bs = -1.0f;
    int bk = 0;
#pragma unroll
    for (int k = 0; k < 16; ++k) {
      float dx = __fsub_rn(px[k], lx);
      float dy = __fsub_rn(py[k], ly);
      float dz = __fsub_rn(pz[k], lz);
      float d  = __fadd_rn(__fadd_rn(__fmul_rn(dx, dx), __fmul_rn(dy, dy)),
                           __fmul_rn(dz, dz));
      float m = fminf(mind[k], d);
      mind[k] = m;
      float sc = __fmul_rn(m, w[k]);
      bool g = sc > bs;
      bs = g ? sc : bs;
      bk = g ? k : bk;
    }
    unsigned n = (unsigned)t + ((unsigned)bk << 10);
    ull best = ((ull)__float_as_uint(bs) << 32) | (ull)(~n);
#pragma unroll
    for (int off = 32; off > 0; off >>= 1) {
      ull o = __shfl_xor(best, off, 64);
      best = (o > best) ? o : best;
    }
    if ((t & 63) == 0) atomicMax(&wmax[s], best);
    __syncthreads();
    best = wmax[s];
    int cur = (int)(~(unsigned)best);
    if (t == 0) idx_out[b * FPS_S + s] = cur;
    const float* qq = xb + 3 * cur;
    lx = qq[0]; ly = qq[1]; lz = qq[2];
  }
}

// ---- gathers ----------------------------------------------------------------
__global__ void gather_kernel(
    const float* __restrict__ xyz,    // [B,N,3]
    const float* __restrict__ feat,   // [B,C,N]
    const int*   __restrict__ label,  // [B,N]
    const int*   __restrict__ idx,    // [B,S]
    float*       __restrict__ out)
{
  const long long FEAT = (long long)FPS_B * FPS_C * FPS_S;  // 2097152
  const int XYZN = FPS_B * FPS_S * 3;                       // 49152
  const int LABN = FPS_B * FPS_S;                           // 16384
  long long i = (long long)blockIdx.x * blockDim.x + threadIdx.x;

  if (i < FEAT) {
    int s = (int)(i & (FPS_S - 1));
    int c = (int)((i >> 10) & (FPS_C - 1));
    int b = (int)(i >> 17);
    int n = idx[b * FPS_S + s];
    out[XYZN + i] = feat[((long long)(b * FPS_C + c)) * FPS_N + n];
  } else if (i < FEAT + XYZN) {
    int j = (int)(i - FEAT);
    int d = j % 3;
    int sb = j / 3;
    int s = sb & (FPS_S - 1);
    int b = sb >> 10;
    int n = idx[b * FPS_S + s];
    out[j] = xyz[((long long)b * FPS_N + n) * 3 + d];
  } else if (i < FEAT + XYZN + LABN) {
    int j = (int)(i - FEAT - XYZN);
    int s = j & (FPS_S - 1);
    int b = j >> 10;
    int n = idx[b * FPS_S + s];
    out[FEAT + XYZN + j] = (float)label[b * FPS_N + n];
  }
}

extern "C" void kernel_launch(void* const* d_in, const int* in_sizes, int n_in,
                              void* d_out, int out_size, void* d_ws, size_t ws_size,
                              hipStream_t stream) {
  const float* xyz   = (const float*)d_in[0];
  const float* feat  = (const float*)d_in[1];
  const int*   label = (const int*)d_in[2];
  float* out = (float*)d_out;

  int* idx    = (int*)d_ws;                        // [0, 64K): idx int[16][1024]
  int* counts = (int*)((char*)d_ws + 65536);       // [64K, 66K): int[16][32]
  ull* slots  = (ull*)((char*)d_ws + 67584);       // [66K, 82K): ull[16][64][2]

  const size_t need = 65536 + 2048 + (size_t)FPS_B * FPS_Q * 2 * 8;  // 83968

  if (ws_size >= need) {
    wfps_prep<<<FPS_B, 1024, 0, stream>>>(label, counts, slots);
    wfps_fps<<<FPS_B * FPS_Q, 64, 0, stream>>>(xyz, label, counts, idx, slots);
  } else {
    wfps_single<<<FPS_B, 1024, 0, stream>>>(xyz, label, idx);
  }

  const long long total = (long long)FPS_B * FPS_C * FPS_S
                        + (long long)FPS_B * FPS_S * 3
                        + (long long)FPS_B * FPS_S;  // 2162688
  gather_kernel<<<(int)((total + 255) / 256), 256, 0, stream>>>(
      xyz, feat, label, idx, out);
}

// Round 11
// 2421.908 us; speedup vs baseline: 1.8433x; 1.8433x over previous
//
#include <hip/hip_runtime.h>

// Weighted furthest point sampling + gathers for KeypointDetector.
// B=16, N=16384, C=128, S=1024, SEM=20.
//
// FPS: one 1024-thread block per batch (16 CUs). Per step: per-lane argmax
// over 16 resident points -> in-wave DPP+shfl max -> per-wave owner writes
// {score|~n, x,y,z} record to LDS -> ONE barrier -> every wave DPP-reduces
// the 16 records; winner coords come from the record (no global reload,
// no LDS atomics on the critical path).
//
// Output layout (float*, concatenated in reference return order):
//   [0, 49152)                  sampled_xyz      [B,S,3]
//   [49152, 49152+2097152)      sample_seg_feat  [B,C,S]
//   [2146304, 2162688)          sample_seg_label [B,S] (stored as float)

#define FPS_B   16
#define FPS_N   16384
#define FPS_C   128
#define FPS_S   1024
#define FPS_SEM 20
#define FPS_T   1024
#define FPS_PPT 16   // points per thread = N / T

typedef unsigned long long ull;

// 64-bit max with a DPP-permuted partner (VALU-only, ~4cyc/op). Proven on HW
// in R10's passing run. CTRL: 0xB1=xor1, 0x4E=xor2, 0x141=row_half_mirror
// (merges 4-halves of each 8), 0x140=row_mirror (merges 8-halves of each 16).
template <int CTRL>
__device__ __forceinline__ ull dpp_max64(ull v) {
  unsigned lo = (unsigned)v, hi = (unsigned)(v >> 32);
  unsigned plo = __builtin_amdgcn_update_dpp(lo, lo, CTRL, 0xF, 0xF, true);
  unsigned phi = __builtin_amdgcn_update_dpp(hi, hi, CTRL, 0xF, 0xF, true);
  ull o = ((ull)phi << 32) | plo;
  return o > v ? o : v;
}

__device__ __forceinline__ ull dpp_max16(ull v) {  // max within each 16-group
  v = dpp_max64<0xB1>(v);
  v = dpp_max64<0x4E>(v);
  v = dpp_max64<0x141>(v);
  v = dpp_max64<0x140>(v);
  return v;
}

__global__ __launch_bounds__(FPS_T)
__attribute__((amdgpu_waves_per_eu(4, 4)))
void wfps_kernel(
    const float* __restrict__ xyz,    // [B,N,3]
    const int*   __restrict__ label,  // [B,N]
    int*         __restrict__ idx_out) // [B,S]
{
  const int b = blockIdx.x;
  const int t = threadIdx.x;
  const int wave = t >> 6;
  const int lane = t & 63;

  __shared__ int counts[FPS_SEM];
  __shared__ ull wbest[2][16];          // per-wave winner, double-buffered
  __shared__ unsigned wcoord[2][16][4]; // per-wave winner coords (x,y,z)

  if (t < FPS_SEM) counts[t] = 0;
  __syncthreads();

  // ---- class-frequency weights ----
  const int* lab = label + b * FPS_N;
  int mylab[FPS_PPT];
#pragma unroll
  for (int k = 0; k < FPS_PPT; ++k) {
    mylab[k] = lab[t + k * FPS_T];
    atomicAdd(&counts[mylab[k]], 1);
  }
  __syncthreads();

  // ---- my 16 points in registers; n = t + k*1024 ----
  const float* xb = xyz + b * FPS_N * 3;
  float px[FPS_PPT], py[FPS_PPT], pz[FPS_PPT], w[FPS_PPT], mind[FPS_PPT];
#pragma unroll
  for (int k = 0; k < FPS_PPT; ++k) {
    int n = t + k * FPS_T;
    px[k] = xb[n * 3 + 0];
    py[k] = xb[n * 3 + 1];
    pz[k] = xb[n * 3 + 2];
    w[k] = (float)counts[mylab[k]];
    mind[k] = 1e10f;
    asm("" : "+v"(px[k]), "+v"(py[k]), "+v"(pz[k]), "+v"(w[k]));
  }

  if (t == 0) idx_out[b * FPS_S] = 0;
  float lx = xb[0], ly = xb[1], lz = xb[2];

  // ---- serial FPS loop ----
  for (int s = 1; s < FPS_S; ++s) {
    // local best over my 16 points (strict '>' keeps smallest k == smallest n)
    float bs = -1.0f;
    int bk = 0;
#pragma unroll
    for (int k = 0; k < FPS_PPT; ++k) {
      // exact IEEE ops via _rn intrinsics: un-fusable, numpy summation order
      float dx = __fsub_rn(px[k], lx);
      float dy = __fsub_rn(py[k], ly);
      float dz = __fsub_rn(pz[k], lz);
      float d  = __fadd_rn(__fadd_rn(__fmul_rn(dx, dx), __fmul_rn(dy, dy)),
                           __fmul_rn(dz, dz));
      float m = fminf(mind[k], d);
      mind[k] = m;
      float sc = __fmul_rn(m, w[k]);
      bool g = sc > bs;
      bs = g ? sc : bs;
      bk = g ? k : bk;   // k inline constant -> no index array
    }
    // pack (score_bits, ~n): u64 max == (max score, then smallest index)
    unsigned n = (unsigned)t + ((unsigned)bk << 10);
    ull best = ((ull)__float_as_uint(bs) << 32) | (ull)(~n);

    // in-wave max: 4 VALU DPP levels + 2 shfl crossings (16, 32)
    best = dpp_max16(best);
    { ull o = __shfl_xor(best, 16, 64); best = (o > best) ? o : best;
      o = __shfl_xor(best, 32, 64);     best = (o > best) ? o : best; }

    // owner lane (holds the wave winner's bk) writes this wave's record
    int wn = (int)(~(unsigned)best);          // wave-winner index n
    if (lane == (wn & 63)) {
      float sx = px[0], sy = py[0], sz = pz[0];
#pragma unroll
      for (int k = 1; k < FPS_PPT; ++k)       // static indices only
        if (bk == k) { sx = px[k]; sy = py[k]; sz = pz[k]; }
      wbest[s & 1][wave] = best;
      wcoord[s & 1][wave][0] = __float_as_uint(sx);
      wcoord[s & 1][wave][1] = __float_as_uint(sy);
      wcoord[s & 1][wave][2] = __float_as_uint(sz);
    }
    __syncthreads();

    // every wave reduces the 16 records in-register (4 DPP levels)
    ull v = wbest[s & 1][lane & 15];
    v = dpp_max16(v);                          // uniform across the wave
    int cur = (int)(~(unsigned)v);             // global winner index
    int r = (cur >> 6) & 15;                   // winner's wave == record id

    lx = __uint_as_float(wcoord[s & 1][r][0]); // uniform LDS broadcast reads
    ly = __uint_as_float(wcoord[s & 1][r][1]);
    lz = __uint_as_float(wcoord[s & 1][r][2]);

    if (t == 0) idx_out[b * FPS_S + s] = cur;
  }
}

// ---- gathers ----------------------------------------------------------------
__global__ void gather_kernel(
    const float* __restrict__ xyz,    // [B,N,3]
    const float* __restrict__ feat,   // [B,C,N]
    const int*   __restrict__ label,  // [B,N]
    const int*   __restrict__ idx,    // [B,S]
    float*       __restrict__ out)
{
  const long long FEAT = (long long)FPS_B * FPS_C * FPS_S;  // 2097152
  const int XYZN = FPS_B * FPS_S * 3;                       // 49152
  const int LABN = FPS_B * FPS_S;                           // 16384
  long long i = (long long)blockIdx.x * blockDim.x + threadIdx.x;

  if (i < FEAT) {
    int s = (int)(i & (FPS_S - 1));
    int c = (int)((i >> 10) & (FPS_C - 1));
    int b = (int)(i >> 17);
    int n = idx[b * FPS_S + s];
    out[XYZN + i] = feat[((long long)(b * FPS_C + c)) * FPS_N + n];
  } else if (i < FEAT + XYZN) {
    int j = (int)(i - FEAT);
    int d = j % 3;
    int sb = j / 3;
    int s = sb & (FPS_S - 1);
    int b = sb >> 10;
    int n = idx[b * FPS_S + s];
    out[j] = xyz[((long long)b * FPS_N + n) * 3 + d];
  } else if (i < FEAT + XYZN + LABN) {
    int j = (int)(i - FEAT - XYZN);
    int s = j & (FPS_S - 1);
    int b = j >> 10;
    int n = idx[b * FPS_S + s];
    out[FEAT + XYZN + j] = (float)label[b * FPS_N + n];
  }
}

extern "C" void kernel_launch(void* const* d_in, const int* in_sizes, int n_in,
                              void* d_out, int out_size, void* d_ws, size_t ws_size,
                              hipStream_t stream) {
  const float* xyz   = (const float*)d_in[0];
  const float* feat  = (const float*)d_in[1];
  const int*   label = (const int*)d_in[2];
  float* out = (float*)d_out;
  int*   idx = (int*)d_ws;  // B*S ints = 64 KiB scratch

  wfps_kernel<<<FPS_B, FPS_T, 0, stream>>>(xyz, label, idx);

  const long long total = (long long)FPS_B * FPS_C * FPS_S
                        + (long long)FPS_B * FPS_S * 3
                        + (long long)FPS_B * FPS_S;  // 2162688
  gather_kernel<<<(int)((total + 255) / 256), 256, 0, stream>>>(
      xyz, feat, label, idx, out);
}

// Round 12
// 1639.434 us; speedup vs baseline: 2.7231x; 1.4773x over previous
//
#include <hip/hip_runtime.h>

// Weighted furthest point sampling + gathers for KeypointDetector.
// B=16, N=16384, C=128, S=1024, SEM=20.
//
// FPS: one 1024-thread block per batch. Per step:
//   per-lane argmax over 16 resident points (exact IEEE, numpy order)
//   -> in-wave f32 max (4 DPP v_max levels + 2 32-bit shfls)
//   -> wave leaders atomicMax(u32 score bits) into per-step LDS slot
//   -> barrier -> threads matching the global max atomicMin their index
//   -> barrier -> cur; coords via uniform cached load.
// 32-bit reduce everywhere: value-max == bit-max since scores >= +0.
//
// Output layout (float*, concatenated in reference return order):
//   [0, 49152)                  sampled_xyz      [B,S,3]
//   [49152, 49152+2097152)      sample_seg_feat  [B,C,S]
//   [2146304, 2162688)          sample_seg_label [B,S] (stored as float)

#define FPS_B   16
#define FPS_N   16384
#define FPS_C   128
#define FPS_S   1024
#define FPS_SEM 20
#define FPS_T   1024
#define FPS_PPT 16   // points per thread = N / T

typedef unsigned long long ull;

// f32 lane permute via DPP (VALU-only). CTRL: 0xB1=xor1, 0x4E=xor2,
// 0x141=row_half_mirror (xor7 merge), 0x140=row_mirror (xor15 merge).
// Proven on HW in R10/R11 runs.
template <int CTRL>
__device__ __forceinline__ float dpp_movf(float v) {
  return __uint_as_float(__builtin_amdgcn_update_dpp(
      __float_as_uint(v), __float_as_uint(v), CTRL, 0xF, 0xF, true));
}

__global__ __launch_bounds__(FPS_T)
__attribute__((amdgpu_waves_per_eu(4, 4)))
void wfps_kernel(
    const float* __restrict__ xyz,    // [B,N,3]
    const int*   __restrict__ label,  // [B,N]
    int*         __restrict__ idx_out) // [B,S]
{
  const int b = blockIdx.x;
  const int t = threadIdx.x;
  const int lane = t & 63;

  __shared__ int counts[FPS_SEM];
  __shared__ unsigned wmax32[FPS_S];  // per-step max score bits (init 0)
  __shared__ int widx[FPS_S];         // per-step winner index (init MAX)

  if (t < FPS_SEM) counts[t] = 0;
  wmax32[t] = 0u;            // T == FPS_S: each thread inits one slot
  widx[t] = 0x7FFFFFFF;      // single-use slots: no per-step re-init
  __syncthreads();

  // ---- class-frequency weights ----
  const int* lab = label + b * FPS_N;
  int mylab[FPS_PPT];
#pragma unroll
  for (int k = 0; k < FPS_PPT; ++k) {
    mylab[k] = lab[t + k * FPS_T];
    atomicAdd(&counts[mylab[k]], 1);
  }
  __syncthreads();

  // ---- my 16 points in registers; n = t + k*1024 ----
  const float* xb = xyz + b * FPS_N * 3;
  float px[FPS_PPT], py[FPS_PPT], pz[FPS_PPT], w[FPS_PPT], mind[FPS_PPT];
#pragma unroll
  for (int k = 0; k < FPS_PPT; ++k) {
    int n = t + k * FPS_T;
    px[k] = xb[n * 3 + 0];
    py[k] = xb[n * 3 + 1];
    pz[k] = xb[n * 3 + 2];
    w[k] = (float)counts[mylab[k]];
    mind[k] = 1e10f;
    asm("" : "+v"(px[k]), "+v"(py[k]), "+v"(pz[k]), "+v"(w[k]));
  }

  if (t == 0) idx_out[b * FPS_S] = 0;
  float lx = xb[0], ly = xb[1], lz = xb[2];

  // ---- serial FPS loop ----
  for (int s = 1; s < FPS_S; ++s) {
    // local best over my 16 points (strict '>' keeps smallest k == smallest n)
    float bs = -1.0f;
    int bk = 0;
#pragma unroll
    for (int k = 0; k < FPS_PPT; ++k) {
      // exact IEEE ops via _rn intrinsics: un-fusable, numpy summation order
      float dx = __fsub_rn(px[k], lx);
      float dy = __fsub_rn(py[k], ly);
      float dz = __fsub_rn(pz[k], lz);
      float d  = __fadd_rn(__fadd_rn(__fmul_rn(dx, dx), __fmul_rn(dy, dy)),
                           __fmul_rn(dz, dz));
      float m = fminf(mind[k], d);
      mind[k] = m;
      float sc = __fmul_rn(m, w[k]);
      bool g = sc > bs;
      bs = g ? sc : bs;
      bk = g ? k : bk;   // k inline constant -> no index array
    }

    // in-wave f32 max, value only: 4 DPP levels + 2 32-bit shfls.
    // scores >= +0 (w >= 1, d >= +0) so bit order == value order, no NaNs.
    float m = bs;
    m = fmaxf(m, dpp_movf<0xB1>(m));
    m = fmaxf(m, dpp_movf<0x4E>(m));
    m = fmaxf(m, dpp_movf<0x141>(m));
    m = fmaxf(m, dpp_movf<0x140>(m));
    m = fmaxf(m, __shfl_xor(m, 16, 64));
    m = fmaxf(m, __shfl_xor(m, 32, 64));

    if (lane == 0) atomicMax(&wmax32[s], __float_as_uint(m));
    __syncthreads();

    // phase 2: candidate threads (typically exactly one) race min-index
    unsigned M = wmax32[s];
    if (__float_as_uint(bs) == M)
      atomicMin(&widx[s], t + (bk << 10));
    __syncthreads();

    int cur = widx[s];
    if (t == 0) idx_out[b * FPS_S + s] = cur;

    // selected point coords: uniform cached load (L1 hit after first touch)
    const float* q = xb + 3 * cur;
    lx = q[0]; ly = q[1]; lz = q[2];
  }
}

// ---- gathers ----------------------------------------------------------------
__global__ void gather_kernel(
    const float* __restrict__ xyz,    // [B,N,3]
    const float* __restrict__ feat,   // [B,C,N]
    const int*   __restrict__ label,  // [B,N]
    const int*   __restrict__ idx,    // [B,S]
    float*       __restrict__ out)
{
  const long long FEAT = (long long)FPS_B * FPS_C * FPS_S;  // 2097152
  const int XYZN = FPS_B * FPS_S * 3;                       // 49152
  const int LABN = FPS_B * FPS_S;                           // 16384
  long long i = (long long)blockIdx.x * blockDim.x + threadIdx.x;

  if (i < FEAT) {
    int s = (int)(i & (FPS_S - 1));
    int c = (int)((i >> 10) & (FPS_C - 1));
    int b = (int)(i >> 17);
    int n = idx[b * FPS_S + s];
    out[XYZN + i] = feat[((long long)(b * FPS_C + c)) * FPS_N + n];
  } else if (i < FEAT + XYZN) {
    int j = (int)(i - FEAT);
    int d = j % 3;
    int sb = j / 3;
    int s = sb & (FPS_S - 1);
    int b = sb >> 10;
    int n = idx[b * FPS_S + s];
    out[j] = xyz[((long long)b * FPS_N + n) * 3 + d];
  } else if (i < FEAT + XYZN + LABN) {
    int j = (int)(i - FEAT - XYZN);
    int s = j & (FPS_S - 1);
    int b = j >> 10;
    int n = idx[b * FPS_S + s];
    out[FEAT + XYZN + j] = (float)label[b * FPS_N + n];
  }
}

extern "C" void kernel_launch(void* const* d_in, const int* in_sizes, int n_in,
                              void* d_out, int out_size, void* d_ws, size_t ws_size,
                              hipStream_t stream) {
  const float* xyz   = (const float*)d_in[0];
  const float* feat  = (const float*)d_in[1];
  const int*   label = (const int*)d_in[2];
  float* out = (float*)d_out;
  int*   idx = (int*)d_ws;  // B*S ints = 64 KiB scratch

  wfps_kernel<<<FPS_B, FPS_T, 0, stream>>>(xyz, label, idx);

  const long long total = (long long)FPS_B * FPS_C * FPS_S
                        + (long long)FPS_B * FPS_S * 3
                        + (long long)FPS_B * FPS_S;  // 2162688
  gather_kernel<<<(int)((total + 255) / 256), 256, 0, stream>>>(
      xyz, feat, label, idx, out);
}

// Round 13
// 1630.675 us; speedup vs baseline: 2.7377x; 1.0054x over previous
//
#include <hip/hip_runtime.h>

// Weighted furthest point sampling + gathers for KeypointDetector.
// B=16, N=16384, C=128, S=1024, SEM=20.
//
// FPS: one 1024-thread block per batch. Per step:
//   per-lane argmax over 16 resident points (exact IEEE, numpy order)
//   -> in-wave f32 max (4 DPP v_max levels + 2 32-bit shfls)
//   -> wave leaders atomicMax(u32 score bits) into per-step LDS slot
//   -> barrier -> threads matching the global max atomicMin their index
//   -> barrier -> cur; coords via scalar (uniform) cached load.
// 32-bit reduce everywhere: value-max == bit-max since scores >= +0.
//
// R12 showed VGPR_Count=52 for ~100 live floats: the allocator parks the
// point arrays in AGPRs and pays v_accvgpr_read/write on every use (~96
// VALU inst/wave/step — the dominant non-mandatory cost in an issue-bound
// loop). amdgpu_agpr_alloc(0) forbids AGPR allocation so state must stay
// in arch VGPRs (~110 <= 128 budget at 4 waves/EU). Guarded: degrades to
// exactly R12 if the attribute is unsupported.
//
// Output layout (float*, concatenated in reference return order):
//   [0, 49152)                  sampled_xyz      [B,S,3]
//   [49152, 49152+2097152)      sample_seg_feat  [B,C,S]
//   [2146304, 2162688)          sample_seg_label [B,S] (stored as float)

#define FPS_B   16
#define FPS_N   16384
#define FPS_C   128
#define FPS_S   1024
#define FPS_SEM 20
#define FPS_T   1024
#define FPS_PPT 16   // points per thread = N / T

#if defined(__has_attribute)
#if __has_attribute(amdgpu_agpr_alloc)
#define FPS_NO_AGPR __attribute__((amdgpu_agpr_alloc(0)))
#else
#define FPS_NO_AGPR
#endif
#else
#define FPS_NO_AGPR
#endif

typedef unsigned long long ull;

// f32 lane permute via DPP (VALU-only). CTRL: 0xB1=xor1, 0x4E=xor2,
// 0x141=row_half_mirror (xor7 merge), 0x140=row_mirror (xor15 merge).
// Proven on HW in R10/R11/R12 runs.
template <int CTRL>
__device__ __forceinline__ float dpp_movf(float v) {
  return __uint_as_float(__builtin_amdgcn_update_dpp(
      __float_as_uint(v), __float_as_uint(v), CTRL, 0xF, 0xF, true));
}

__global__ __launch_bounds__(FPS_T)
__attribute__((amdgpu_waves_per_eu(4, 4)))
FPS_NO_AGPR
void wfps_kernel(
    const float* __restrict__ xyz,    // [B,N,3]
    const int*   __restrict__ label,  // [B,N]
    int*         __restrict__ idx_out) // [B,S]
{
  const int b = blockIdx.x;
  const int t = threadIdx.x;
  const int lane = t & 63;

  __shared__ int counts[FPS_SEM];
  __shared__ unsigned wmax32[FPS_S];  // per-step max score bits (init 0)
  __shared__ int widx[FPS_S];         // per-step winner index (init MAX)

  if (t < FPS_SEM) counts[t] = 0;
  wmax32[t] = 0u;            // T == FPS_S: each thread inits one slot
  widx[t] = 0x7FFFFFFF;      // single-use slots: no per-step re-init
  __syncthreads();

  // ---- class-frequency weights ----
  const int* lab = label + b * FPS_N;
  int mylab[FPS_PPT];
#pragma unroll
  for (int k = 0; k < FPS_PPT; ++k) {
    mylab[k] = lab[t + k * FPS_T];
    atomicAdd(&counts[mylab[k]], 1);
  }
  __syncthreads();

  // ---- my 16 points in registers; n = t + k*1024 ----
  const float* xb = xyz + b * FPS_N * 3;
  float px[FPS_PPT], py[FPS_PPT], pz[FPS_PPT], w[FPS_PPT], mind[FPS_PPT];
#pragma unroll
  for (int k = 0; k < FPS_PPT; ++k) {
    int n = t + k * FPS_T;
    px[k] = xb[n * 3 + 0];
    py[k] = xb[n * 3 + 1];
    pz[k] = xb[n * 3 + 2];
    w[k] = (float)counts[mylab[k]];
    mind[k] = 1e10f;
    asm("" : "+v"(px[k]), "+v"(py[k]), "+v"(pz[k]), "+v"(w[k]));
  }

  if (t == 0) idx_out[b * FPS_S] = 0;
  float lx = xb[0], ly = xb[1], lz = xb[2];

  // ---- serial FPS loop ----
  for (int s = 1; s < FPS_S; ++s) {
    // local best over my 16 points (strict '>' keeps smallest k == smallest n)
    float bs = -1.0f;
    int bk = 0;
#pragma unroll
    for (int k = 0; k < FPS_PPT; ++k) {
      // exact IEEE ops via _rn intrinsics: un-fusable, numpy summation order
      float dx = __fsub_rn(px[k], lx);
      float dy = __fsub_rn(py[k], ly);
      float dz = __fsub_rn(pz[k], lz);
      float d  = __fadd_rn(__fadd_rn(__fmul_rn(dx, dx), __fmul_rn(dy, dy)),
                           __fmul_rn(dz, dz));
      float m = fminf(mind[k], d);
      mind[k] = m;
      float sc = __fmul_rn(m, w[k]);
      bool g = sc > bs;
      bs = g ? sc : bs;
      bk = g ? k : bk;   // k inline constant -> no index array
    }

    // in-wave f32 max, value only: 4 DPP levels + 2 32-bit shfls.
    // scores >= +0 (w >= 1, d >= +0) so bit order == value order, no NaNs.
    float m = bs;
    m = fmaxf(m, dpp_movf<0xB1>(m));
    m = fmaxf(m, dpp_movf<0x4E>(m));
    m = fmaxf(m, dpp_movf<0x141>(m));
    m = fmaxf(m, dpp_movf<0x140>(m));
    m = fmaxf(m, __shfl_xor(m, 16, 64));
    m = fmaxf(m, __shfl_xor(m, 32, 64));

    if (lane == 0) atomicMax(&wmax32[s], __float_as_uint(m));
    __syncthreads();

    // phase 2: candidate threads (typically exactly one) race min-index
    unsigned M = wmax32[s];
    if (__float_as_uint(bs) == M)
      atomicMin(&widx[s], t + (bk << 10));
    __syncthreads();

    int cur = __builtin_amdgcn_readfirstlane(widx[s]);  // provably uniform
    if (t == 0) idx_out[b * FPS_S + s] = cur;

    // selected point coords: scalar/SMEM path (uniform address, cache-hot)
    const float* q = xb + 3 * cur;
    lx = q[0]; ly = q[1]; lz = q[2];
  }
}

// ---- gathers ----------------------------------------------------------------
__global__ void gather_kernel(
    const float* __restrict__ xyz,    // [B,N,3]
    const float* __restrict__ feat,   // [B,C,N]
    const int*   __restrict__ label,  // [B,N]
    const int*   __restrict__ idx,    // [B,S]
    float*       __restrict__ out)
{
  const long long FEAT = (long long)FPS_B * FPS_C * FPS_S;  // 2097152
  const int XYZN = FPS_B * FPS_S * 3;                       // 49152
  const int LABN = FPS_B * FPS_S;                           // 16384
  long long i = (long long)blockIdx.x * blockDim.x + threadIdx.x;

  if (i < FEAT) {
    int s = (int)(i & (FPS_S - 1));
    int c = (int)((i >> 10) & (FPS_C - 1));
    int b = (int)(i >> 17);
    int n = idx[b * FPS_S + s];
    out[XYZN + i] = feat[((long long)(b * FPS_C + c)) * FPS_N + n];
  } else if (i < FEAT + XYZN) {
    int j = (int)(i - FEAT);
    int d = j % 3;
    int sb = j / 3;
    int s = sb & (FPS_S - 1);
    int b = sb >> 10;
    int n = idx[b * FPS_S + s];
    out[j] = xyz[((long long)b * FPS_N + n) * 3 + d];
  } else if (i < FEAT + XYZN + LABN) {
    int j = (int)(i - FEAT - XYZN);
    int s = j & (FPS_S - 1);
    int b = j >> 10;
    int n = idx[b * FPS_S + s];
    out[FEAT + XYZN + j] = (float)label[b * FPS_N + n];
  }
}

extern "C" void kernel_launch(void* const* d_in, const int* in_sizes, int n_in,
                              void* d_out, int out_size, void* d_ws, size_t ws_size,
                              hipStream_t stream) {
  const float* xyz   = (const float*)d_in[0];
  const float* feat  = (const float*)d_in[1];
  const int*   label = (const int*)d_in[2];
  float* out = (float*)d_out;
  int*   idx = (int*)d_ws;  // B*S ints = 64 KiB scratch

  wfps_kernel<<<FPS_B, FPS_T, 0, stream>>>(xyz, label, idx);

  const long long total = (long long)FPS_B * FPS_C * FPS_S
                        + (long long)FPS_B * FPS_S * 3
                        + (long long)FPS_B * FPS_S;  // 2162688
  gather_kernel<<<(int)((total + 255) / 256), 256, 0, stream>>>(
      xyz, feat, label, idx, out);
}